// Round 5
// baseline (287.534 us; speedup 1.0000x reference)
//
#include <hip/hip_runtime.h>
#include <math.h>

// ---------------------------------------------------------------------------
// MultiHeadAttention: B=8, S=1024, H=12, D=768, DH=64. fp32 in/out.
// R12: attention = R9's read-amortized 4 waves x 32 q-rows (halved LDS
// reads/FLOP, correctness-proven) but with SINGLE-buffered K/V: LDS
// 8+8+16 = 32 KB -> 5 blocks/CU = 20 waves/CU on the balanced 768-block
// grid. Fixes R9's occupancy loss (12 waves/CU) while keeping its LDS-cycle
// cut; staging latency (L2-resident K/V) is covered by 5 independent
// blocks/CU at different phases. Two barriers per kt (stage->compute).
// qkv/out/prep unchanged.
// ---------------------------------------------------------------------------

constexpr int NB  = 8;
constexpr int SEQ = 1024;
constexpr int NH  = 12;
constexpr int DM  = 768;
constexpr int DHD = 64;
constexpr int MROWS = NB * SEQ;      // 8192
constexpr int NQKV  = 3 * NH * DHD;  // 2304

typedef __attribute__((ext_vector_type(8))) short short8;
typedef __attribute__((ext_vector_type(4))) float f32x4;

#define MFMA16(a,b,c) __builtin_amdgcn_mfma_f32_16x16x32_bf16((a),(b),(c),0,0,0)

#if __has_builtin(__builtin_amdgcn_exp2f)
#define EXP2(x) __builtin_amdgcn_exp2f(x)
#else
#define EXP2(x) exp2f(x)
#endif

// RNE float->bf16
__device__ __forceinline__ unsigned short f2bf(float f) {
    unsigned u = __float_as_uint(f);
    return (unsigned short)((u + 0x7fffu + ((u >> 16) & 1u)) >> 16);
}
// round-half-up float->bf16 (2 VALU) — P in the attention hot loop
__device__ __forceinline__ unsigned short f2bf_fast(float f) {
    return (unsigned short)((__float_as_uint(f) + 0x8000u) >> 16);
}

// async 16B/lane global->LDS (LDS dest wave-uniform base + lane*16)
__device__ __forceinline__ void gl_lds16(const unsigned short* g, unsigned short* l) {
    __builtin_amdgcn_global_load_lds(
        (const __attribute__((address_space(1))) void*)g,
        (__attribute__((address_space(3))) void*)l, 16, 0, 0);
}

// 128B-row tiles ([rows][64] bf16), swizzle: chunk at pos (c+r)&7.
// One call stages rows [i*8, i*8+8) (1 KB).
__device__ __forceinline__ void stageK(unsigned short* lds, const unsigned short* gbase,
                                       int i, int ln, int ldg) {
    int r    = i * 8 + (ln >> 3);
    int cpos = ln & 7;
    int cdat = (cpos - r) & 7;
    gl_lds16(gbase + (size_t)r * ldg + cdat * 8, lds + i * 512);
}
__device__ __forceinline__ short8 ldK(const unsigned short* buf, int row, int chunk) {
    int c = (chunk + row) & 7;
    return *(const short8*)&buf[row * 64 + c * 8];
}

// ---------------------------------------------------------------------------
// Fused prep: blocks [0,6144) convert x fp32->bf16; blocks [6144,6720)
// transpose+convert Wq/Wk/Wv (per-head [768][64] -> [64][768]) and Wo.
// ---------------------------------------------------------------------------
__global__ __launch_bounds__(256) void prep_k(
    const float* __restrict__ x,
    const float* __restrict__ Wq, const float* __restrict__ Wk,
    const float* __restrict__ Wv, const float* __restrict__ Wo,
    unsigned short* __restrict__ xb, unsigned short* __restrict__ wt,
    unsigned short* __restrict__ wot) {
    __shared__ float tb[64][65];
    const int blk = blockIdx.x, tid = threadIdx.x;
    if (blk < 6144) {  // x conversion: 6144*256 float4 = elsX
        const int i = blk * 256 + tid;
        float4 v = ((const float4*)x)[i];
        ushort4 o;
        o.x = f2bf(v.x); o.y = f2bf(v.y); o.z = f2bf(v.z); o.w = f2bf(v.w);
        ((ushort4*)xb)[i] = o;
        return;
    }
    const int t = blk - 6144;       // 0..575
    const int job = t / 144, lb = t % 144;
    const float* W;
    unsigned short* dst;
    int C, r0, c0;
    if (job < 3) {
        const float* Ws = (job == 0) ? Wq : (job == 1 ? Wk : Wv);
        const int h = lb / 12, rb = lb % 12;
        W = Ws + (size_t)h * (DM * DHD);                // [768][64]
        dst = wt + (size_t)(job * 12 + h) * (DM * DHD); // rows = e, cols = d
        C = DHD; r0 = rb * 64; c0 = 0;
    } else {
        W = Wo; dst = wot; C = DM;
        r0 = (lb / 12) * 64; c0 = (lb % 12) * 64;
    }
    const int rr = tid >> 2, cc = (tid & 3) * 16;
#pragma unroll
    for (int j = 0; j < 16; j += 4) {
        float4 v = *(const float4*)&W[(size_t)(r0 + rr) * C + c0 + cc + j];
        tb[rr][cc + j + 0] = v.x;
        tb[rr][cc + j + 1] = v.y;
        tb[rr][cc + j + 2] = v.z;
        tb[rr][cc + j + 3] = v.w;
    }
    __syncthreads();
#pragma unroll
    for (int j = 0; j < 16; ++j)
        dst[(size_t)(c0 + rr) * DM + r0 + cc + j] = f2bf(tb[cc + j][rr]);
}

// ---------------------------------------------------------------------------
// Kernel 1: QKV projection. Tile 128x128, BK=64, single-buffered, 2x2 waves.
// q/k blocks transposed orientation (packed ushort4 epilogue); v normal
// (packed along seq into vT). Grid (64, 18). UNCHANGED from R6.
// ---------------------------------------------------------------------------
__global__ __launch_bounds__(256, 3) void qkv_mfma_k(
    const unsigned short* __restrict__ xb, const unsigned short* __restrict__ wt,
    const float* __restrict__ bq, const float* __restrict__ bk, const float* __restrict__ bv,
    unsigned short* __restrict__ qb, unsigned short* __restrict__ kb,
    unsigned short* __restrict__ vT) {
    __shared__ unsigned short Ah[128 * 64], Bh[128 * 64];   // 16 KB + 16 KB

    const int tid = threadIdx.x;
    const int wv = tid >> 6, ln = tid & 63, quad = ln >> 4, lnid = ln & 15;
    const int wvm = wv >> 1, wvn = wv & 1;
    const int row0 = blockIdx.x * 128, col0 = blockIdx.y * 128;
    const int sel = (col0 >= 2 * DM) ? 2 : (col0 >= DM ? 1 : 0);

    f32x4 acc[4][4];
#pragma unroll
    for (int i = 0; i < 4; ++i)
#pragma unroll
        for (int j = 0; j < 4; ++j) acc[i][j] = (f32x4){0.f, 0.f, 0.f, 0.f};

    const unsigned short* Ahg = xb + (size_t)row0 * DM;
    const unsigned short* Bhg = wt + (size_t)col0 * DM;
    constexpr int NIT = DM / 64;  // 12

    if (sel < 2) {
        // ---- transposed: acc[et][st], D rows = e, cols = srow ----
        for (int it = 0; it < NIT; ++it) {
            const int kc = it * 64;
            __syncthreads();
#pragma unroll
            for (int c = 0; c < 4; ++c) {
                stageK(Ah, Ahg + kc, wv * 4 + c, ln, DM);
                stageK(Bh, Bhg + kc, wv * 4 + c, ln, DM);
            }
            __syncthreads();
#pragma unroll
            for (int ks = 0; ks < 2; ++ks) {
                short8 a[4], b[4];
#pragma unroll
                for (int i = 0; i < 4; ++i)
                    a[i] = ldK(Ah, wvm * 64 + i * 16 + lnid, ks * 4 + quad);
#pragma unroll
                for (int j = 0; j < 4; ++j)
                    b[j] = ldK(Bh, wvn * 64 + j * 16 + lnid, ks * 4 + quad);
#pragma unroll
                for (int j = 0; j < 4; ++j)
#pragma unroll
                    for (int i = 0; i < 4; ++i)
                        acc[j][i] = MFMA16(b[j], a[i], acc[j][i]);
            }
        }
        // q prescale folds 1/sqrt(64) and log2(e) so softmax is bare exp2
        const float scale = (sel == 0) ? 0.18033688011112042f : 1.0f;
        const float* bias = (sel == 0) ? bq : bk;
        unsigned short* oh = (sel == 0) ? qb : kb;
#pragma unroll
        for (int et = 0; et < 4; ++et) {
            const int e = col0 + wvn * 64 + et * 16 + quad * 4;
            const int he = e - sel * DM;
            const int hh2 = he >> 6, ee = he & 63;
            float4 bs = *(const float4*)&bias[he];
#pragma unroll
            for (int st = 0; st < 4; ++st) {
                const int srow = row0 + wvm * 64 + st * 16 + lnid;
                const int bb = srow >> 10, ss = srow & (SEQ - 1);
                ushort4 pk;
                pk.x = f2bf((acc[et][st][0] + bs.x) * scale);
                pk.y = f2bf((acc[et][st][1] + bs.y) * scale);
                pk.z = f2bf((acc[et][st][2] + bs.z) * scale);
                pk.w = f2bf((acc[et][st][3] + bs.w) * scale);
                *(ushort4*)&oh[((size_t)(bb * NH + hh2) * SEQ + ss) * DHD + ee] = pk;
            }
        }
    } else {
        // ---- normal: acc[st][et], D rows = srow, cols = e; packed along s ----
        for (int it = 0; it < NIT; ++it) {
            const int kc = it * 64;
            __syncthreads();
#pragma unroll
            for (int c = 0; c < 4; ++c) {
                stageK(Ah, Ahg + kc, wv * 4 + c, ln, DM);
                stageK(Bh, Bhg + kc, wv * 4 + c, ln, DM);
            }
            __syncthreads();
#pragma unroll
            for (int ks = 0; ks < 2; ++ks) {
                short8 a[4], b[4];
#pragma unroll
                for (int i = 0; i < 4; ++i)
                    a[i] = ldK(Ah, wvm * 64 + i * 16 + lnid, ks * 4 + quad);
#pragma unroll
                for (int j = 0; j < 4; ++j)
                    b[j] = ldK(Bh, wvn * 64 + j * 16 + lnid, ks * 4 + quad);
#pragma unroll
                for (int i = 0; i < 4; ++i)
#pragma unroll
                    for (int j = 0; j < 4; ++j)
                        acc[i][j] = MFMA16(a[i], b[j], acc[i][j]);
            }
        }
#pragma unroll
        for (int i = 0; i < 4; ++i) {
#pragma unroll
            for (int j = 0; j < 4; ++j) {
                const int col = col0 + wvn * 64 + j * 16 + lnid;
                const int he = col - 2 * DM;
                const int hh2 = he >> 6, ee = he & 63;
                const float bs = bv[he];
                const int srow = row0 + wvm * 64 + i * 16 + quad * 4;
                const int bb = srow >> 10, ss = srow & (SEQ - 1);
                ushort4 pk;
                pk.x = f2bf(acc[i][j][0] + bs);
                pk.y = f2bf(acc[i][j][1] + bs);
                pk.z = f2bf(acc[i][j][2] + bs);
                pk.w = f2bf(acc[i][j][3] + bs);
                *(ushort4*)&vT[((size_t)(bb * NH + hh2) * DHD + ee) * SEQ + ss] = pk;
            }
        }
    }
}

// ---------------------------------------------------------------------------
// Kernel 2: flash attention. 256 threads = 4 waves, each wave 32 q-rows
// (2 row-groups of 16; kf/vf fragments reused across both -> halved LDS
// reads per FLOP, R9-proven math). K/V SINGLE-buffered: LDS 8+8+16 = 32 KB
// -> 5 blocks/CU = 20 waves/CU (R9's dbuf gave only 12 -> latency-bound).
// Per kt: [bar] stage K/V(kt) [bar] QK -> exp/P-writes -> PV. Staging
// latency (K/V L2-resident, 8 blocks share each bh) hidden by 5 independent
// blocks/CU at different phases. Grid 768 1-D, bh = blk % 96 fastest.
// ---------------------------------------------------------------------------
__global__ __launch_bounds__(256, 5) void attn_mfma_k(
    const unsigned short* __restrict__ qb, const unsigned short* __restrict__ kb,
    const unsigned short* __restrict__ vT, unsigned short* __restrict__ ctb) {
    __shared__ unsigned short ksh[64 * 64], vsm[64 * 64];   // 8 KB + 8 KB
    __shared__ unsigned short ps[128 * 64];                 // 16 KB, XOR-8 swizzled

    const int tid = threadIdx.x;
    const int wv = tid >> 6, ln = tid & 63, quad = ln >> 4, lnid = ln & 15;
    const int bhid = blockIdx.x % 96, qt = blockIdx.x / 96;
    const int b = bhid / NH, h = bhid % NH;
    const int q0 = qt * 128;
    const unsigned short* qhb = qb + (size_t)bhid * (SEQ * DHD);
    const unsigned short* khb = kb + (size_t)bhid * (SEQ * DHD);
    const unsigned short* vTb = vT + (size_t)bhid * (DHD * SEQ);

    const int prow0 = wv * 32 + lnid;   // rg=0 q-row; rg=1 is prow0+16

    // persistent q fragments (B-operand: lane&15 = qrow) [rg][kstep]
    short8 qf[2][2];
#pragma unroll
    for (int rg = 0; rg < 2; ++rg)
#pragma unroll
        for (int ks_ = 0; ks_ < 2; ++ks_)
            qf[rg][ks_] = *(const short8*)(qhb +
                (size_t)(q0 + prow0 + rg * 16) * DHD + ks_ * 32 + quad * 8);

    f32x4 ctx[2][4];   // [rg][dt]: D rows = d, cols = qrow
#pragma unroll
    for (int rg = 0; rg < 2; ++rg)
#pragma unroll
        for (int j = 0; j < 4; ++j) ctx[rg][j] = (f32x4){0.f, 0.f, 0.f, 0.f};
    float lsum0 = 0.f, lsum1 = 0.f;

    for (int kt = 0; kt < SEQ / 64; ++kt) {
        __syncthreads();   // prev iter's K/V readers done
        // stage current tile (wave wv stages rows [wv*16, wv*16+16) of each)
        stageK(ksh, khb + kt * 64 * DHD, wv * 2 + 0, ln, DHD);
        stageK(ksh, khb + kt * 64 * DHD, wv * 2 + 1, ln, DHD);
        stageK(vsm, vTb + kt * 64, wv * 2 + 0, ln, SEQ);
        stageK(vsm, vTb + kt * 64, wv * 2 + 1, ln, SEQ);
        __syncthreads();   // K/V staged (barrier drains vmcnt)

        // ---- scores S^T: sc[rg][nt] rows = kv (nt*16+quad*4+r), cols = qrow
        //      kf loaded once, reused for both row-groups (LDS amortization)
        f32x4 sc[2][4];
#pragma unroll
        for (int rg = 0; rg < 2; ++rg)
#pragma unroll
            for (int j = 0; j < 4; ++j) sc[rg][j] = (f32x4){0.f, 0.f, 0.f, 0.f};
#pragma unroll
        for (int ks_ = 0; ks_ < 2; ++ks_) {
#pragma unroll
            for (int nt = 0; nt < 4; ++nt) {
                short8 kf = ldK(ksh, nt * 16 + lnid, ks_ * 4 + quad);
                sc[0][nt] = MFMA16(kf, qf[0][ks_], sc[0][nt]);
                sc[1][nt] = MFMA16(kf, qf[1][ks_], sc[1][nt]);
            }
        }

        // ---- p = 2^s; per-lane sums; swizzled b64 P-writes (wave-private) --
#pragma unroll
        for (int rg = 0; rg < 2; ++rg) {
            const int prow = prow0 + rg * 16;
#pragma unroll
            for (int nt = 0; nt < 4; ++nt) {
                float p0 = EXP2(sc[rg][nt][0]);
                float p1 = EXP2(sc[rg][nt][1]);
                float p2 = EXP2(sc[rg][nt][2]);
                float p3 = EXP2(sc[rg][nt][3]);
                if (rg == 0) lsum0 += (p0 + p1) + (p2 + p3);
                else         lsum1 += (p0 + p1) + (p2 + p3);
                ushort4 pw;
                pw.x = f2bf_fast(p0);
                pw.y = f2bf_fast(p1);
                pw.z = f2bf_fast(p2);
                pw.w = f2bf_fast(p3);
                // chunk cdat = 2*nt + (quad>>1), swizzled pos (cdat + prow) & 7
                const int cpos = (2 * nt + (quad >> 1) + prow) & 7;
                *(ushort4*)&ps[prow * 64 + cpos * 8 + (quad & 1) * 4] = pw;
            }
        }

        // ---- PV: ctx^T += MFMA(V^T, P); vf loaded once, both row-groups ---
#pragma unroll
        for (int kvs = 0; kvs < 2; ++kvs) {
            short8 pf0 = ldK(ps, prow0,      kvs * 4 + quad);
            short8 pf1 = ldK(ps, prow0 + 16, kvs * 4 + quad);
#pragma unroll
            for (int dt = 0; dt < 4; ++dt) {
                short8 vf = ldK(vsm, dt * 16 + lnid, kvs * 4 + quad);
                ctx[0][dt] = MFMA16(vf, pf0, ctx[0][dt]);
                ctx[1][dt] = MFMA16(vf, pf1, ctx[1][dt]);
            }
        }
    }

    // ---- row sums (reduce over quads: 2 shuffles), packed ushort4 stores --
#pragma unroll
    for (int rg = 0; rg < 2; ++rg) {
        float s = (rg == 0) ? lsum0 : lsum1;
        s += __shfl_xor(s, 16, 64);
        s += __shfl_xor(s, 32, 64);
        const float inv = 1.0f / s;
        const int srow = b * SEQ + q0 + prow0 + rg * 16;
#pragma unroll
        for (int dt = 0; dt < 4; ++dt) {
            ushort4 pk;
            pk.x = f2bf(ctx[rg][dt][0] * inv);
            pk.y = f2bf(ctx[rg][dt][1] * inv);
            pk.z = f2bf(ctx[rg][dt][2] * inv);
            pk.w = f2bf(ctx[rg][dt][3] * inv);
            *(ushort4*)&ctb[(size_t)srow * DM + h * DHD + dt * 16 + quad * 4] = pk;
        }
    }
}

// ---------------------------------------------------------------------------
// Kernel 3: output projection. Tile 128x64, BK=64, single-buffered,
// transposed orientation -> float4 stores. Grid (64, 12) = 768 blocks.
// UNCHANGED from R6.
// ---------------------------------------------------------------------------
__global__ __launch_bounds__(256, 3) void out_mfma_k(
    const unsigned short* __restrict__ ctb, const unsigned short* __restrict__ wot,
    const float* __restrict__ bo, float* __restrict__ out) {
    __shared__ unsigned short Ah[128 * 64], Bh[64 * 64];   // 16 KB + 8 KB

    const int tid = threadIdx.x;
    const int wv = tid >> 6, ln = tid & 63, quad = ln >> 4, lnid = ln & 15;
    const int wvm = wv >> 1, wvn = wv & 1;
    const int row0 = blockIdx.x * 128, col0 = blockIdx.y * 64;

    f32x4 acc[2][4];   // [jt][it]: D rows = outcol, cols = srow
#pragma unroll
    for (int j = 0; j < 2; ++j)
#pragma unroll
        for (int i = 0; i < 4; ++i) acc[j][i] = (f32x4){0.f, 0.f, 0.f, 0.f};

    const unsigned short* Ahg = ctb + (size_t)row0 * DM;
    const unsigned short* Bhg = wot + (size_t)col0 * DM;

    constexpr int NIT = DM / 64;  // 12
    for (int it = 0; it < NIT; ++it) {
        const int kc = it * 64;
        __syncthreads();
#pragma unroll
        for (int c = 0; c < 4; ++c) stageK(Ah, Ahg + kc, wv * 4 + c, ln, DM);
#pragma unroll
        for (int c = 0; c < 2; ++c) stageK(Bh, Bhg + kc, wv * 2 + c, ln, DM);
        __syncthreads();
#pragma unroll
        for (int ks = 0; ks < 2; ++ks) {
            short8 a[4], b[2];
#pragma unroll
            for (int i = 0; i < 4; ++i)
                a[i] = ldK(Ah, wvm * 64 + i * 16 + lnid, ks * 4 + quad);
#pragma unroll
            for (int j = 0; j < 2; ++j)
                b[j] = ldK(Bh, wvn * 32 + j * 16 + lnid, ks * 4 + quad);
#pragma unroll
            for (int j = 0; j < 2; ++j)
#pragma unroll
                for (int i = 0; i < 4; ++i)
                    acc[j][i] = MFMA16(b[j], a[i], acc[j][i]);
        }
    }

#pragma unroll
    for (int jt = 0; jt < 2; ++jt) {
        const int colb = col0 + wvn * 32 + jt * 16 + quad * 4;
        float4 bs = *(const float4*)&bo[colb];
#pragma unroll
        for (int it = 0; it < 4; ++it) {
            const int srow = row0 + wvm * 64 + it * 16 + lnid;
            float4 o;
            o.x = acc[jt][it][0] + bs.x;
            o.y = acc[jt][it][1] + bs.y;
            o.z = acc[jt][it][2] + bs.z;
            o.w = acc[jt][it][3] + bs.w;
            *(float4*)&out[(size_t)srow * DM + colb] = o;
        }
    }
}

// ---------------------------------------------------------------------------
extern "C" void kernel_launch(void* const* d_in, const int* in_sizes, int n_in,
                              void* d_out, int out_size, void* d_ws, size_t ws_size,
                              hipStream_t stream) {
    const float* x  = (const float*)d_in[0];
    const float* Wq = (const float*)d_in[1];
    const float* Wk = (const float*)d_in[2];
    const float* Wv = (const float*)d_in[3];
    const float* bq = (const float*)d_in[4];
    const float* bk = (const float*)d_in[5];
    const float* bv = (const float*)d_in[6];
    const float* Wo = (const float*)d_in[7];
    const float* bo = (const float*)d_in[8];
    float* out = (float*)d_out;

    // workspace: xb | wt | wot | qb | kb | vT. ctb aliases xb (disjoint lifetime).
    char* w = (char*)d_ws;
    const size_t elsX = (size_t)MROWS * DM;          // 6,291,456
    const size_t elsQ = (size_t)NB * NH * SEQ * DHD; // 6,291,456
    unsigned short* xb  = (unsigned short*)w;
    unsigned short* ctb = xb;  // alias, disjoint lifetime
    size_t off = elsX * 2;
    unsigned short* wt  = (unsigned short*)(w + off); off += (size_t)NQKV * DM * 2;
    unsigned short* wot = (unsigned short*)(w + off); off += (size_t)DM * DM * 2;
    unsigned short* qbp = (unsigned short*)(w + off); off += elsQ * 2;
    unsigned short* kbp = (unsigned short*)(w + off); off += elsQ * 2;
    unsigned short* vTp = (unsigned short*)(w + off); off += elsQ * 2;

    prep_k<<<dim3(6144 + 576), 256, 0, stream>>>(x, Wq, Wk, Wv, Wo, xb, wt, wot);
    qkv_mfma_k<<<dim3(MROWS / 128, NQKV / 128), 256, 0, stream>>>(
        xb, wt, bq, bk, bv, qbp, kbp, vTp);
    attn_mfma_k<<<dim3(768), 256, 0, stream>>>(qbp, kbp, vTp, ctb);
    out_mfma_k<<<dim3(MROWS / 128, DM / 64), 256, 0, stream>>>(ctb, wot, bo, out);
}

// Round 6
// 198.476 us; speedup vs baseline: 1.4487x; 1.4487x over previous
//
#include <hip/hip_runtime.h>
#include <math.h>

// ---------------------------------------------------------------------------
// MultiHeadAttention: B=8, S=1024, H=12, D=768, DH=64. fp32 in/out.
// R13: attention reverted to the R7-proven 8-wave dbuf kernel (43.0 us;
// R12's single-buffer destroyed inter-block L2 reuse: FETCH 20->194 MB —
// dbuf prefetch is the rate-synchronizer that keeps co-bh blocks L2-
// coherent). Experiment: qkv double-buffered (stage it+1 overlaps compute
// of it, one barrier/iter — same skeleton as R7 attn) to remove the
// per-K-step vmcnt drain; LDS 32->64 KB, 2 blocks/CU. out/prep unchanged.
// ---------------------------------------------------------------------------

constexpr int NB  = 8;
constexpr int SEQ = 1024;
constexpr int NH  = 12;
constexpr int DM  = 768;
constexpr int DHD = 64;
constexpr int MROWS = NB * SEQ;      // 8192
constexpr int NQKV  = 3 * NH * DHD;  // 2304

typedef __attribute__((ext_vector_type(8))) short short8;
typedef __attribute__((ext_vector_type(4))) float f32x4;

#define MFMA16(a,b,c) __builtin_amdgcn_mfma_f32_16x16x32_bf16((a),(b),(c),0,0,0)

#if __has_builtin(__builtin_amdgcn_exp2f)
#define EXP2(x) __builtin_amdgcn_exp2f(x)
#else
#define EXP2(x) exp2f(x)
#endif

// RNE float->bf16
__device__ __forceinline__ unsigned short f2bf(float f) {
    unsigned u = __float_as_uint(f);
    return (unsigned short)((u + 0x7fffu + ((u >> 16) & 1u)) >> 16);
}
// round-half-up float->bf16 (2 VALU) — P in the attention hot loop
__device__ __forceinline__ unsigned short f2bf_fast(float f) {
    return (unsigned short)((__float_as_uint(f) + 0x8000u) >> 16);
}

// async 16B/lane global->LDS (LDS dest wave-uniform base + lane*16)
__device__ __forceinline__ void gl_lds16(const unsigned short* g, unsigned short* l) {
    __builtin_amdgcn_global_load_lds(
        (const __attribute__((address_space(1))) void*)g,
        (__attribute__((address_space(3))) void*)l, 16, 0, 0);
}

// 128B-row tiles ([rows][64] bf16), swizzle: chunk at pos (c+r)&7.
// One call stages rows [i*8, i*8+8) (1 KB).
__device__ __forceinline__ void stageK(unsigned short* lds, const unsigned short* gbase,
                                       int i, int ln, int ldg) {
    int r    = i * 8 + (ln >> 3);
    int cpos = ln & 7;
    int cdat = (cpos - r) & 7;
    gl_lds16(gbase + (size_t)r * ldg + cdat * 8, lds + i * 512);
}
__device__ __forceinline__ short8 ldK(const unsigned short* buf, int row, int chunk) {
    int c = (chunk + row) & 7;
    return *(const short8*)&buf[row * 64 + c * 8];
}

// ---------------------------------------------------------------------------
// Fused prep: blocks [0,6144) convert x fp32->bf16; blocks [6144,6720)
// transpose+convert Wq/Wk/Wv (per-head [768][64] -> [64][768]) and Wo.
// ---------------------------------------------------------------------------
__global__ __launch_bounds__(256) void prep_k(
    const float* __restrict__ x,
    const float* __restrict__ Wq, const float* __restrict__ Wk,
    const float* __restrict__ Wv, const float* __restrict__ Wo,
    unsigned short* __restrict__ xb, unsigned short* __restrict__ wt,
    unsigned short* __restrict__ wot) {
    __shared__ float tb[64][65];
    const int blk = blockIdx.x, tid = threadIdx.x;
    if (blk < 6144) {  // x conversion: 6144*256 float4 = elsX
        const int i = blk * 256 + tid;
        float4 v = ((const float4*)x)[i];
        ushort4 o;
        o.x = f2bf(v.x); o.y = f2bf(v.y); o.z = f2bf(v.z); o.w = f2bf(v.w);
        ((ushort4*)xb)[i] = o;
        return;
    }
    const int t = blk - 6144;       // 0..575
    const int job = t / 144, lb = t % 144;
    const float* W;
    unsigned short* dst;
    int C, r0, c0;
    if (job < 3) {
        const float* Ws = (job == 0) ? Wq : (job == 1 ? Wk : Wv);
        const int h = lb / 12, rb = lb % 12;
        W = Ws + (size_t)h * (DM * DHD);                // [768][64]
        dst = wt + (size_t)(job * 12 + h) * (DM * DHD); // rows = e, cols = d
        C = DHD; r0 = rb * 64; c0 = 0;
    } else {
        W = Wo; dst = wot; C = DM;
        r0 = (lb / 12) * 64; c0 = (lb % 12) * 64;
    }
    const int rr = tid >> 2, cc = (tid & 3) * 16;
#pragma unroll
    for (int j = 0; j < 16; j += 4) {
        float4 v = *(const float4*)&W[(size_t)(r0 + rr) * C + c0 + cc + j];
        tb[rr][cc + j + 0] = v.x;
        tb[rr][cc + j + 1] = v.y;
        tb[rr][cc + j + 2] = v.z;
        tb[rr][cc + j + 3] = v.w;
    }
    __syncthreads();
#pragma unroll
    for (int j = 0; j < 16; ++j)
        dst[(size_t)(c0 + rr) * DM + r0 + cc + j] = f2bf(tb[cc + j][rr]);
}

// ---------------------------------------------------------------------------
// Kernel 1: QKV projection. Tile 128x128, BK=64, DOUBLE-buffered (stage of
// tile it+1 overlaps compute of tile it; one barrier per iter — removes the
// per-K-step vmcnt drain measured as the dominant stall: MfmaUtil 25%,
// VALUBusy 17%, HBM 19%). LDS 64 KB -> 2 blocks/CU. 2x2 waves; q/k blocks
// transposed orientation; v normal (packed along seq into vT). Grid (64,18).
// ---------------------------------------------------------------------------
__global__ __launch_bounds__(256, 2) void qkv_mfma_k(
    const unsigned short* __restrict__ xb, const unsigned short* __restrict__ wt,
    const float* __restrict__ bq, const float* __restrict__ bk, const float* __restrict__ bv,
    unsigned short* __restrict__ qb, unsigned short* __restrict__ kb,
    unsigned short* __restrict__ vT) {
    __shared__ unsigned short Ah[2][128 * 64], Bh[2][128 * 64];   // 32 KB + 32 KB

    const int tid = threadIdx.x;
    const int wv = tid >> 6, ln = tid & 63, quad = ln >> 4, lnid = ln & 15;
    const int wvm = wv >> 1, wvn = wv & 1;
    const int row0 = blockIdx.x * 128, col0 = blockIdx.y * 128;
    const int sel = (col0 >= 2 * DM) ? 2 : (col0 >= DM ? 1 : 0);

    f32x4 acc[4][4];
#pragma unroll
    for (int i = 0; i < 4; ++i)
#pragma unroll
        for (int j = 0; j < 4; ++j) acc[i][j] = (f32x4){0.f, 0.f, 0.f, 0.f};

    const unsigned short* Ahg = xb + (size_t)row0 * DM;
    const unsigned short* Bhg = wt + (size_t)col0 * DM;
    constexpr int NIT = DM / 64;  // 12

    // prefetch tile 0 into buffer 0
#pragma unroll
    for (int c = 0; c < 4; ++c) {
        stageK(Ah[0], Ahg, wv * 4 + c, ln, DM);
        stageK(Bh[0], Bhg, wv * 4 + c, ln, DM);
    }

    if (sel < 2) {
        // ---- transposed: acc[et][st], D rows = e, cols = srow ----
        for (int it = 0; it < NIT; ++it) {
            const int cur = it & 1;
            __syncthreads();   // buf[cur] ready; prev readers of buf[cur^1] done
            if (it + 1 < NIT) {
                const int kc = (it + 1) * 64;
#pragma unroll
                for (int c = 0; c < 4; ++c) {
                    stageK(Ah[cur ^ 1], Ahg + kc, wv * 4 + c, ln, DM);
                    stageK(Bh[cur ^ 1], Bhg + kc, wv * 4 + c, ln, DM);
                }
            }
#pragma unroll
            for (int ks = 0; ks < 2; ++ks) {
                short8 a[4], b[4];
#pragma unroll
                for (int i = 0; i < 4; ++i)
                    a[i] = ldK(Ah[cur], wvm * 64 + i * 16 + lnid, ks * 4 + quad);
#pragma unroll
                for (int j = 0; j < 4; ++j)
                    b[j] = ldK(Bh[cur], wvn * 64 + j * 16 + lnid, ks * 4 + quad);
#pragma unroll
                for (int j = 0; j < 4; ++j)
#pragma unroll
                    for (int i = 0; i < 4; ++i)
                        acc[j][i] = MFMA16(b[j], a[i], acc[j][i]);
            }
        }
        // q prescale folds 1/sqrt(64) and log2(e) so softmax is bare exp2
        const float scale = (sel == 0) ? 0.18033688011112042f : 1.0f;
        const float* bias = (sel == 0) ? bq : bk;
        unsigned short* oh = (sel == 0) ? qb : kb;
#pragma unroll
        for (int et = 0; et < 4; ++et) {
            const int e = col0 + wvn * 64 + et * 16 + quad * 4;
            const int he = e - sel * DM;
            const int hh2 = he >> 6, ee = he & 63;
            float4 bs = *(const float4*)&bias[he];
#pragma unroll
            for (int st = 0; st < 4; ++st) {
                const int srow = row0 + wvm * 64 + st * 16 + lnid;
                const int bb = srow >> 10, ss = srow & (SEQ - 1);
                ushort4 pk;
                pk.x = f2bf((acc[et][st][0] + bs.x) * scale);
                pk.y = f2bf((acc[et][st][1] + bs.y) * scale);
                pk.z = f2bf((acc[et][st][2] + bs.z) * scale);
                pk.w = f2bf((acc[et][st][3] + bs.w) * scale);
                *(ushort4*)&oh[((size_t)(bb * NH + hh2) * SEQ + ss) * DHD + ee] = pk;
            }
        }
    } else {
        // ---- normal: acc[st][et], D rows = srow, cols = e; packed along s ----
        for (int it = 0; it < NIT; ++it) {
            const int cur = it & 1;
            __syncthreads();
            if (it + 1 < NIT) {
                const int kc = (it + 1) * 64;
#pragma unroll
                for (int c = 0; c < 4; ++c) {
                    stageK(Ah[cur ^ 1], Ahg + kc, wv * 4 + c, ln, DM);
                    stageK(Bh[cur ^ 1], Bhg + kc, wv * 4 + c, ln, DM);
                }
            }
#pragma unroll
            for (int ks = 0; ks < 2; ++ks) {
                short8 a[4], b[4];
#pragma unroll
                for (int i = 0; i < 4; ++i)
                    a[i] = ldK(Ah[cur], wvm * 64 + i * 16 + lnid, ks * 4 + quad);
#pragma unroll
                for (int j = 0; j < 4; ++j)
                    b[j] = ldK(Bh[cur], wvn * 64 + j * 16 + lnid, ks * 4 + quad);
#pragma unroll
                for (int i = 0; i < 4; ++i)
#pragma unroll
                    for (int j = 0; j < 4; ++j)
                        acc[i][j] = MFMA16(a[i], b[j], acc[i][j]);
            }
        }
#pragma unroll
        for (int i = 0; i < 4; ++i) {
#pragma unroll
            for (int j = 0; j < 4; ++j) {
                const int col = col0 + wvn * 64 + j * 16 + lnid;
                const int he = col - 2 * DM;
                const int hh2 = he >> 6, ee = he & 63;
                const float bs = bv[he];
                const int srow = row0 + wvm * 64 + i * 16 + quad * 4;
                const int bb = srow >> 10, ss = srow & (SEQ - 1);
                ushort4 pk;
                pk.x = f2bf(acc[i][j][0] + bs);
                pk.y = f2bf(acc[i][j][1] + bs);
                pk.z = f2bf(acc[i][j][2] + bs);
                pk.w = f2bf(acc[i][j][3] + bs);
                *(ushort4*)&vT[((size_t)(bb * NH + hh2) * DHD + ee) * SEQ + ss] = pk;
            }
        }
    }
}

// ---------------------------------------------------------------------------
// Kernel 2: flash attention. 512 threads = 8 waves, each wave 16 q-rows.
// Q-tile 128, KV-step 64, K/V double-buffered; 2 stageK calls/wave/iter.
// S^T = MFMA(K,Q); ps XOR-8 swizzled [128][64] (wave-private rows, no extra
// barrier); PV: ctx^T = MFMA(V^T, P). Grid 768 1-D, bh = blk % 96 fastest
// (XCD-local KV). LDS: 16 + 16 + 16 = 48 KB -> 3 blocks/CU = 24 waves/CU.
// EXACT R7 kernel (measured 43.0 us).
// ---------------------------------------------------------------------------
__global__ __launch_bounds__(512, 6) void attn_mfma_k(
    const unsigned short* __restrict__ qb, const unsigned short* __restrict__ kb,
    const unsigned short* __restrict__ vT, unsigned short* __restrict__ ctb) {
    __shared__ unsigned short ksh[2][64 * 64], vsm[2][64 * 64];
    __shared__ unsigned short ps[128 * 64];   // XOR-8 swizzled

    const int tid = threadIdx.x;
    const int wv = tid >> 6, ln = tid & 63, quad = ln >> 4, lnid = ln & 15;
    const int bhid = blockIdx.x % 96, qt = blockIdx.x / 96;
    const int b = bhid / NH, h = bhid % NH;
    const int q0 = qt * 128;
    const unsigned short* qhb = qb + (size_t)bhid * (SEQ * DHD);
    const unsigned short* khb = kb + (size_t)bhid * (SEQ * DHD);
    const unsigned short* vTb = vT + (size_t)bhid * (DHD * SEQ);

    const int prow = wv * 16 + lnid;   // this lane's block-local q-row

    // persistent q fragment (B-operand: lane&15 = qrow) [kstep]
    short8 qf[2];
#pragma unroll
    for (int ks_ = 0; ks_ < 2; ++ks_)
        qf[ks_] = *(const short8*)(qhb + (size_t)(q0 + prow) * DHD + ks_ * 32 + quad * 8);

    f32x4 ctx[4];   // [dt]: D rows = d, cols = qrow
#pragma unroll
    for (int j = 0; j < 4; ++j) ctx[j] = (f32x4){0.f, 0.f, 0.f, 0.f};
    float lsum = 0.f;

    // prefetch tile 0 into buffer 0 (wave wv stages rows [wv*8, wv*8+8))
    stageK(ksh[0], khb, wv, ln, DHD);
    stageK(vsm[0], vTb, wv, ln, SEQ);

    for (int kt = 0; kt < SEQ / 64; ++kt) {
        const int cur = kt & 1;
        __syncthreads();   // buf[cur] ready; prev readers of buf[cur^1] done
        if (kt + 1 < SEQ / 64) {
            stageK(ksh[cur ^ 1], khb + (kt + 1) * 64 * DHD, wv, ln, DHD);
            stageK(vsm[cur ^ 1], vTb + (kt + 1) * 64, wv, ln, SEQ);
        }

        // ---- scores S^T: sc[nt] rows = j (nt*16+quad*4+r), cols = qrow ----
        f32x4 sc[4];
#pragma unroll
        for (int j = 0; j < 4; ++j) sc[j] = (f32x4){0.f, 0.f, 0.f, 0.f};
#pragma unroll
        for (int ks_ = 0; ks_ < 2; ++ks_) {
#pragma unroll
            for (int nt = 0; nt < 4; ++nt) {
                short8 kf = ldK(ksh[cur], nt * 16 + lnid, ks_ * 4 + quad);
                sc[nt] = MFMA16(kf, qf[ks_], sc[nt]);
            }
        }

        // ---- p = 2^s; per-lane sums; swizzled b64 P-writes (wave-private) ----
#pragma unroll
        for (int nt = 0; nt < 4; ++nt) {
            float p0 = EXP2(sc[nt][0]);
            float p1 = EXP2(sc[nt][1]);
            float p2 = EXP2(sc[nt][2]);
            float p3 = EXP2(sc[nt][3]);
            lsum += (p0 + p1) + (p2 + p3);
            ushort4 pw;
            pw.x = f2bf_fast(p0);
            pw.y = f2bf_fast(p1);
            pw.z = f2bf_fast(p2);
            pw.w = f2bf_fast(p3);
            // chunk cdat = 2*nt + (quad>>1), swizzled pos (cdat + prow) & 7
            const int cpos = (2 * nt + (quad >> 1) + prow) & 7;
            *(ushort4*)&ps[prow * 64 + cpos * 8 + (quad & 1) * 4] = pw;
        }

        // ---- PV: ctx^T += MFMA(V^T, P) ----
#pragma unroll
        for (int kvs = 0; kvs < 2; ++kvs) {
            short8 pf = ldK(ps, prow, kvs * 4 + quad);
#pragma unroll
            for (int dt = 0; dt < 4; ++dt) {
                short8 vf = ldK(vsm[cur], dt * 16 + lnid, kvs * 4 + quad);
                ctx[dt] = MFMA16(vf, pf, ctx[dt]);
            }
        }
    }

    // ---- row sum (reduce over quads: 2 shuffles), packed ushort4 stores ----
    float s = lsum;
    s += __shfl_xor(s, 16, 64);
    s += __shfl_xor(s, 32, 64);
    const float inv = 1.0f / s;
    const int srow = b * SEQ + q0 + prow;
#pragma unroll
    for (int dt = 0; dt < 4; ++dt) {
        ushort4 pk;
        pk.x = f2bf(ctx[dt][0] * inv);
        pk.y = f2bf(ctx[dt][1] * inv);
        pk.z = f2bf(ctx[dt][2] * inv);
        pk.w = f2bf(ctx[dt][3] * inv);
        *(ushort4*)&ctb[(size_t)srow * DM + h * DHD + dt * 16 + quad * 4] = pk;
    }
}

// ---------------------------------------------------------------------------
// Kernel 3: output projection. Tile 128x64, BK=64, single-buffered,
// transposed orientation -> float4 stores. Grid (64, 12) = 768 blocks.
// UNCHANGED from R6.
// ---------------------------------------------------------------------------
__global__ __launch_bounds__(256, 3) void out_mfma_k(
    const unsigned short* __restrict__ ctb, const unsigned short* __restrict__ wot,
    const float* __restrict__ bo, float* __restrict__ out) {
    __shared__ unsigned short Ah[128 * 64], Bh[64 * 64];   // 16 KB + 8 KB

    const int tid = threadIdx.x;
    const int wv = tid >> 6, ln = tid & 63, quad = ln >> 4, lnid = ln & 15;
    const int wvm = wv >> 1, wvn = wv & 1;
    const int row0 = blockIdx.x * 128, col0 = blockIdx.y * 64;

    f32x4 acc[2][4];   // [jt][it]: D rows = outcol, cols = srow
#pragma unroll
    for (int j = 0; j < 2; ++j)
#pragma unroll
        for (int i = 0; i < 4; ++i) acc[j][i] = (f32x4){0.f, 0.f, 0.f, 0.f};

    const unsigned short* Ahg = ctb + (size_t)row0 * DM;
    const unsigned short* Bhg = wot + (size_t)col0 * DM;

    constexpr int NIT = DM / 64;  // 12
    for (int it = 0; it < NIT; ++it) {
        const int kc = it * 64;
        __syncthreads();
#pragma unroll
        for (int c = 0; c < 4; ++c) stageK(Ah, Ahg + kc, wv * 4 + c, ln, DM);
#pragma unroll
        for (int c = 0; c < 2; ++c) stageK(Bh, Bhg + kc, wv * 2 + c, ln, DM);
        __syncthreads();
#pragma unroll
        for (int ks = 0; ks < 2; ++ks) {
            short8 a[4], b[2];
#pragma unroll
            for (int i = 0; i < 4; ++i)
                a[i] = ldK(Ah, wvm * 64 + i * 16 + lnid, ks * 4 + quad);
#pragma unroll
            for (int j = 0; j < 2; ++j)
                b[j] = ldK(Bh, wvn * 32 + j * 16 + lnid, ks * 4 + quad);
#pragma unroll
            for (int j = 0; j < 2; ++j)
#pragma unroll
                for (int i = 0; i < 4; ++i)
                    acc[j][i] = MFMA16(b[j], a[i], acc[j][i]);
        }
    }

#pragma unroll
    for (int jt = 0; jt < 2; ++jt) {
        const int colb = col0 + wvn * 32 + jt * 16 + quad * 4;
        float4 bs = *(const float4*)&bo[colb];
#pragma unroll
        for (int it = 0; it < 4; ++it) {
            const int srow = row0 + wvm * 64 + it * 16 + lnid;
            float4 o;
            o.x = acc[jt][it][0] + bs.x;
            o.y = acc[jt][it][1] + bs.y;
            o.z = acc[jt][it][2] + bs.z;
            o.w = acc[jt][it][3] + bs.w;
            *(float4*)&out[(size_t)srow * DM + colb] = o;
        }
    }
}

// ---------------------------------------------------------------------------
extern "C" void kernel_launch(void* const* d_in, const int* in_sizes, int n_in,
                              void* d_out, int out_size, void* d_ws, size_t ws_size,
                              hipStream_t stream) {
    const float* x  = (const float*)d_in[0];
    const float* Wq = (const float*)d_in[1];
    const float* Wk = (const float*)d_in[2];
    const float* Wv = (const float*)d_in[3];
    const float* bq = (const float*)d_in[4];
    const float* bk = (const float*)d_in[5];
    const float* bv = (const float*)d_in[6];
    const float* Wo = (const float*)d_in[7];
    const float* bo = (const float*)d_in[8];
    float* out = (float*)d_out;

    // workspace: xb | wt | wot | qb | kb | vT. ctb aliases xb (disjoint lifetime).
    char* w = (char*)d_ws;
    const size_t elsX = (size_t)MROWS * DM;          // 6,291,456
    const size_t elsQ = (size_t)NB * NH * SEQ * DHD; // 6,291,456
    unsigned short* xb  = (unsigned short*)w;
    unsigned short* ctb = xb;  // alias, disjoint lifetime
    size_t off = elsX * 2;
    unsigned short* wt  = (unsigned short*)(w + off); off += (size_t)NQKV * DM * 2;
    unsigned short* wot = (unsigned short*)(w + off); off += (size_t)DM * DM * 2;
    unsigned short* qbp = (unsigned short*)(w + off); off += elsQ * 2;
    unsigned short* kbp = (unsigned short*)(w + off); off += elsQ * 2;
    unsigned short* vTp = (unsigned short*)(w + off); off += elsQ * 2;

    prep_k<<<dim3(6144 + 576), 256, 0, stream>>>(x, Wq, Wk, Wv, Wo, xb, wt, wot);
    qkv_mfma_k<<<dim3(MROWS / 128, NQKV / 128), 256, 0, stream>>>(
        xb, wt, bq, bk, bv, qbp, kbp, vTp);
    attn_mfma_k<<<dim3(768), 512, 0, stream>>>(qbp, kbp, vTp, ctb);
    out_mfma_k<<<dim3(MROWS / 128, DM / 64), 256, 0, stream>>>(ctb, wot, bo, out);
}

// Round 9
// 197.234 us; speedup vs baseline: 1.4578x; 1.0063x over previous
//
#include <hip/hip_runtime.h>
#include <math.h>

// ---------------------------------------------------------------------------
// MultiHeadAttention: B=8, S=1024, H=12, D=768, DH=64. fp32 in/out.
// R16 = R14 resubmitted again (R14: container failure; R15: GPU acquisition
// timeout — neither ran). qkv = R0's single-buffered kernel (43.0 us,
// measured 4x). attention: KVBLK=32 config threading ALL four measured
// constraints: dbuf (R12: no dbuf -> FETCH 20->194 MB), 768-block grid
// (R11), rg=2 read amortization (R9), >=20 waves/CU (R9 at 12 was
// latency-bound). LDS 8(K dbuf) + 16(V dbuf, 64-kv windows staged every
// 2 kt, read in halves) + 8(ps [128][32]) = 32 KB -> 5 blocks/CU =
// 20 waves/CU. out/prep unchanged.
// ---------------------------------------------------------------------------

constexpr int NB  = 8;
constexpr int SEQ = 1024;
constexpr int NH  = 12;
constexpr int DM  = 768;
constexpr int DHD = 64;
constexpr int MROWS = NB * SEQ;      // 8192
constexpr int NQKV  = 3 * NH * DHD;  // 2304

typedef __attribute__((ext_vector_type(8))) short short8;
typedef __attribute__((ext_vector_type(4))) float f32x4;

#define MFMA16(a,b,c) __builtin_amdgcn_mfma_f32_16x16x32_bf16((a),(b),(c),0,0,0)

#if __has_builtin(__builtin_amdgcn_exp2f)
#define EXP2(x) __builtin_amdgcn_exp2f(x)
#else
#define EXP2(x) exp2f(x)
#endif

// RNE float->bf16
__device__ __forceinline__ unsigned short f2bf(float f) {
    unsigned u = __float_as_uint(f);
    return (unsigned short)((u + 0x7fffu + ((u >> 16) & 1u)) >> 16);
}
// round-half-up float->bf16 (2 VALU) — P in the attention hot loop
__device__ __forceinline__ unsigned short f2bf_fast(float f) {
    return (unsigned short)((__float_as_uint(f) + 0x8000u) >> 16);
}

// async 16B/lane global->LDS (LDS dest wave-uniform base + lane*16)
__device__ __forceinline__ void gl_lds16(const unsigned short* g, unsigned short* l) {
    __builtin_amdgcn_global_load_lds(
        (const __attribute__((address_space(1))) void*)g,
        (__attribute__((address_space(3))) void*)l, 16, 0, 0);
}

// 128B-row tiles ([rows][64] bf16), swizzle: chunk at pos (c+r)&7.
// One call stages rows [i*8, i*8+8) (1 KB).
__device__ __forceinline__ void stageK(unsigned short* lds, const unsigned short* gbase,
                                       int i, int ln, int ldg) {
    int r    = i * 8 + (ln >> 3);
    int cpos = ln & 7;
    int cdat = (cpos - r) & 7;
    gl_lds16(gbase + (size_t)r * ldg + cdat * 8, lds + i * 512);
}
__device__ __forceinline__ short8 ldK(const unsigned short* buf, int row, int chunk) {
    int c = (chunk + row) & 7;
    return *(const short8*)&buf[row * 64 + c * 8];
}
// 64B-row ps tile ([128][32] bf16), swizzle: chunk at pos (c + (r>>1)) & 3.
__device__ __forceinline__ short8 ldP(const unsigned short* buf, int row, int chunk) {
    int c = (chunk + (row >> 1)) & 3;
    return *(const short8*)&buf[row * 32 + c * 8];
}

// ---------------------------------------------------------------------------
// Fused prep: blocks [0,6144) convert x fp32->bf16; blocks [6144,6720)
// transpose+convert Wq/Wk/Wv (per-head [768][64] -> [64][768]) and Wo.
// ---------------------------------------------------------------------------
__global__ __launch_bounds__(256) void prep_k(
    const float* __restrict__ x,
    const float* __restrict__ Wq, const float* __restrict__ Wk,
    const float* __restrict__ Wv, const float* __restrict__ Wo,
    unsigned short* __restrict__ xb, unsigned short* __restrict__ wt,
    unsigned short* __restrict__ wot) {
    __shared__ float tb[64][65];
    const int blk = blockIdx.x, tid = threadIdx.x;
    if (blk < 6144) {  // x conversion: 6144*256 float4 = elsX
        const int i = blk * 256 + tid;
        float4 v = ((const float4*)x)[i];
        ushort4 o;
        o.x = f2bf(v.x); o.y = f2bf(v.y); o.z = f2bf(v.z); o.w = f2bf(v.w);
        ((ushort4*)xb)[i] = o;
        return;
    }
    const int t = blk - 6144;       // 0..575
    const int job = t / 144, lb = t % 144;
    const float* W;
    unsigned short* dst;
    int C, r0, c0;
    if (job < 3) {
        const float* Ws = (job == 0) ? Wq : (job == 1 ? Wk : Wv);
        const int h = lb / 12, rb = lb % 12;
        W = Ws + (size_t)h * (DM * DHD);                // [768][64]
        dst = wt + (size_t)(job * 12 + h) * (DM * DHD); // rows = e, cols = d
        C = DHD; r0 = rb * 64; c0 = 0;
    } else {
        W = Wo; dst = wot; C = DM;
        r0 = (lb / 12) * 64; c0 = (lb % 12) * 64;
    }
    const int rr = tid >> 2, cc = (tid & 3) * 16;
#pragma unroll
    for (int j = 0; j < 16; j += 4) {
        float4 v = *(const float4*)&W[(size_t)(r0 + rr) * C + c0 + cc + j];
        tb[rr][cc + j + 0] = v.x;
        tb[rr][cc + j + 1] = v.y;
        tb[rr][cc + j + 2] = v.z;
        tb[rr][cc + j + 3] = v.w;
    }
    __syncthreads();
#pragma unroll
    for (int j = 0; j < 16; ++j)
        dst[(size_t)(c0 + rr) * DM + r0 + cc + j] = f2bf(tb[cc + j][rr]);
}

// ---------------------------------------------------------------------------
// Kernel 1: QKV projection. Tile 128x128, BK=64, single-buffered, 2x2 waves.
// q/k blocks transposed orientation (packed ushort4 epilogue); v normal
// (packed along seq into vT). Grid (64, 18). EXACT R0 kernel (43.0 us).
// ---------------------------------------------------------------------------
__global__ __launch_bounds__(256, 3) void qkv_mfma_k(
    const unsigned short* __restrict__ xb, const unsigned short* __restrict__ wt,
    const float* __restrict__ bq, const float* __restrict__ bk, const float* __restrict__ bv,
    unsigned short* __restrict__ qb, unsigned short* __restrict__ kb,
    unsigned short* __restrict__ vT) {
    __shared__ unsigned short Ah[128 * 64], Bh[128 * 64];   // 16 KB + 16 KB

    const int tid = threadIdx.x;
    const int wv = tid >> 6, ln = tid & 63, quad = ln >> 4, lnid = ln & 15;
    const int wvm = wv >> 1, wvn = wv & 1;
    const int row0 = blockIdx.x * 128, col0 = blockIdx.y * 128;
    const int sel = (col0 >= 2 * DM) ? 2 : (col0 >= DM ? 1 : 0);

    f32x4 acc[4][4];
#pragma unroll
    for (int i = 0; i < 4; ++i)
#pragma unroll
        for (int j = 0; j < 4; ++j) acc[i][j] = (f32x4){0.f, 0.f, 0.f, 0.f};

    const unsigned short* Ahg = xb + (size_t)row0 * DM;
    const unsigned short* Bhg = wt + (size_t)col0 * DM;
    constexpr int NIT = DM / 64;  // 12

    if (sel < 2) {
        // ---- transposed: acc[et][st], D rows = e, cols = srow ----
        for (int it = 0; it < NIT; ++it) {
            const int kc = it * 64;
            __syncthreads();
#pragma unroll
            for (int c = 0; c < 4; ++c) {
                stageK(Ah, Ahg + kc, wv * 4 + c, ln, DM);
                stageK(Bh, Bhg + kc, wv * 4 + c, ln, DM);
            }
            __syncthreads();
#pragma unroll
            for (int ks = 0; ks < 2; ++ks) {
                short8 a[4], b[4];
#pragma unroll
                for (int i = 0; i < 4; ++i)
                    a[i] = ldK(Ah, wvm * 64 + i * 16 + lnid, ks * 4 + quad);
#pragma unroll
                for (int j = 0; j < 4; ++j)
                    b[j] = ldK(Bh, wvn * 64 + j * 16 + lnid, ks * 4 + quad);
#pragma unroll
                for (int j = 0; j < 4; ++j)
#pragma unroll
                    for (int i = 0; i < 4; ++i)
                        acc[j][i] = MFMA16(b[j], a[i], acc[j][i]);
            }
        }
        // q prescale folds 1/sqrt(64) and log2(e) so softmax is bare exp2
        const float scale = (sel == 0) ? 0.18033688011112042f : 1.0f;
        const float* bias = (sel == 0) ? bq : bk;
        unsigned short* oh = (sel == 0) ? qb : kb;
#pragma unroll
        for (int et = 0; et < 4; ++et) {
            const int e = col0 + wvn * 64 + et * 16 + quad * 4;
            const int he = e - sel * DM;
            const int hh2 = he >> 6, ee = he & 63;
            float4 bs = *(const float4*)&bias[he];
#pragma unroll
            for (int st = 0; st < 4; ++st) {
                const int srow = row0 + wvm * 64 + st * 16 + lnid;
                const int bb = srow >> 10, ss = srow & (SEQ - 1);
                ushort4 pk;
                pk.x = f2bf((acc[et][st][0] + bs.x) * scale);
                pk.y = f2bf((acc[et][st][1] + bs.y) * scale);
                pk.z = f2bf((acc[et][st][2] + bs.z) * scale);
                pk.w = f2bf((acc[et][st][3] + bs.w) * scale);
                *(ushort4*)&oh[((size_t)(bb * NH + hh2) * SEQ + ss) * DHD + ee] = pk;
            }
        }
    } else {
        // ---- normal: acc[st][et], D rows = srow, cols = e; packed along s ----
        for (int it = 0; it < NIT; ++it) {
            const int kc = it * 64;
            __syncthreads();
#pragma unroll
            for (int c = 0; c < 4; ++c) {
                stageK(Ah, Ahg + kc, wv * 4 + c, ln, DM);
                stageK(Bh, Bhg + kc, wv * 4 + c, ln, DM);
            }
            __syncthreads();
#pragma unroll
            for (int ks = 0; ks < 2; ++ks) {
                short8 a[4], b[4];
#pragma unroll
                for (int i = 0; i < 4; ++i)
                    a[i] = ldK(Ah, wvm * 64 + i * 16 + lnid, ks * 4 + quad);
#pragma unroll
                for (int j = 0; j < 4; ++j)
                    b[j] = ldK(Bh, wvn * 64 + j * 16 + lnid, ks * 4 + quad);
#pragma unroll
                for (int i = 0; i < 4; ++i)
#pragma unroll
                    for (int j = 0; j < 4; ++j)
                        acc[i][j] = MFMA16(a[i], b[j], acc[i][j]);
            }
        }
#pragma unroll
        for (int i = 0; i < 4; ++i) {
#pragma unroll
            for (int j = 0; j < 4; ++j) {
                const int col = col0 + wvn * 64 + j * 16 + lnid;
                const int he = col - 2 * DM;
                const int hh2 = he >> 6, ee = he & 63;
                const float bs = bv[he];
                const int srow = row0 + wvm * 64 + i * 16 + quad * 4;
                const int bb = srow >> 10, ss = srow & (SEQ - 1);
                ushort4 pk;
                pk.x = f2bf(acc[i][j][0] + bs);
                pk.y = f2bf(acc[i][j][1] + bs);
                pk.z = f2bf(acc[i][j][2] + bs);
                pk.w = f2bf(acc[i][j][3] + bs);
                *(ushort4*)&vT[((size_t)(bb * NH + hh2) * DHD + ee) * SEQ + ss] = pk;
            }
        }
    }
}

// ---------------------------------------------------------------------------
// Kernel 2: flash attention, KVBLK=32. 256 threads = 4 waves x 32 q-rows
// (2 row-groups; kf/vf reused across both -> R9's halved reads/FLOP).
// K double-buffered per-32-kv tile; V double-buffered as 64-kv windows
// staged every 2 kt and read in 32-kv halves. ps [128][32], swizzle
// (c + (row>>1)) & 3 (b64 writes 4 words/bank, b128 reads conflict-free).
// LDS 8 + 16 + 8 = 32 KB -> 5 blocks/CU = 20 waves/CU; grid 768 balanced.
// ---------------------------------------------------------------------------
__global__ __launch_bounds__(256, 5) void attn_mfma_k(
    const unsigned short* __restrict__ qb, const unsigned short* __restrict__ kb,
    const unsigned short* __restrict__ vT, unsigned short* __restrict__ ctb) {
    __shared__ unsigned short ksh[2][32 * 64];   // 2 x 4 KB
    __shared__ unsigned short vsm[2][64 * 64];   // 2 x 8 KB
    __shared__ unsigned short ps[128 * 32];      // 8 KB

    const int tid = threadIdx.x;
    const int wv = tid >> 6, ln = tid & 63, quad = ln >> 4, lnid = ln & 15;
    const int bhid = blockIdx.x % 96, qt = blockIdx.x / 96;
    const int b = bhid / NH, h = bhid % NH;
    const int q0 = qt * 128;
    const unsigned short* qhb = qb + (size_t)bhid * (SEQ * DHD);
    const unsigned short* khb = kb + (size_t)bhid * (SEQ * DHD);
    const unsigned short* vTb = vT + (size_t)bhid * (DHD * SEQ);

    const int prow0 = wv * 32 + lnid;   // rg=0 q-row; rg=1 is prow0+16

    // persistent q fragments (B-operand: lane&15 = qrow) [rg][kstep]
    short8 qf[2][2];
#pragma unroll
    for (int rg = 0; rg < 2; ++rg)
#pragma unroll
        for (int ks_ = 0; ks_ < 2; ++ks_)
            qf[rg][ks_] = *(const short8*)(qhb +
                (size_t)(q0 + prow0 + rg * 16) * DHD + ks_ * 32 + quad * 8);

    f32x4 ctx[2][4];   // [rg][dt]: D rows = d, cols = qrow
#pragma unroll
    for (int rg = 0; rg < 2; ++rg)
#pragma unroll
        for (int j = 0; j < 4; ++j) ctx[rg][j] = (f32x4){0.f, 0.f, 0.f, 0.f};
    float lsum0 = 0.f, lsum1 = 0.f;

    // prologue: K tile 0 (wave wv stages rows wv*8..wv*8+8 of 32) and
    // V window 0 (wave wv stages d-rows [wv*16, wv*16+16))
    stageK(ksh[0], khb, wv, ln, DHD);
    stageK(vsm[0], vTb, wv * 2 + 0, ln, SEQ);
    stageK(vsm[0], vTb, wv * 2 + 1, ln, SEQ);

    for (int kt = 0; kt < SEQ / 32; ++kt) {     // 32 iterations
        const int kcur = kt & 1;
        const int vt = kt >> 1, vcur = vt & 1, half = kt & 1;
        __syncthreads();   // current buffers staged; prev readers done
        if (kt + 1 < SEQ / 32)
            stageK(ksh[kcur ^ 1], khb + (kt + 1) * 32 * DHD, wv, ln, DHD);
        if (half == 0 && vt + 1 < SEQ / 64) {
            stageK(vsm[vcur ^ 1], vTb + (vt + 1) * 64, wv * 2 + 0, ln, SEQ);
            stageK(vsm[vcur ^ 1], vTb + (vt + 1) * 64, wv * 2 + 1, ln, SEQ);
        }

        // ---- scores S^T: sc[rg][nt], kv = nt*16 + quad*4 + r, col = qrow --
        f32x4 sc[2][2];
#pragma unroll
        for (int rg = 0; rg < 2; ++rg)
#pragma unroll
            for (int j = 0; j < 2; ++j) sc[rg][j] = (f32x4){0.f, 0.f, 0.f, 0.f};
#pragma unroll
        for (int ks_ = 0; ks_ < 2; ++ks_) {
#pragma unroll
            for (int nt = 0; nt < 2; ++nt) {
                short8 kf = ldK(ksh[kcur], nt * 16 + lnid, ks_ * 4 + quad);
                sc[0][nt] = MFMA16(kf, qf[0][ks_], sc[0][nt]);
                sc[1][nt] = MFMA16(kf, qf[1][ks_], sc[1][nt]);
            }
        }

        // ---- p = 2^s; per-lane sums; swizzled b64 P-writes (wave-private) --
#pragma unroll
        for (int rg = 0; rg < 2; ++rg) {
            const int prow = prow0 + rg * 16;
#pragma unroll
            for (int nt = 0; nt < 2; ++nt) {
                float p0 = EXP2(sc[rg][nt][0]);
                float p1 = EXP2(sc[rg][nt][1]);
                float p2 = EXP2(sc[rg][nt][2]);
                float p3 = EXP2(sc[rg][nt][3]);
                if (rg == 0) lsum0 += (p0 + p1) + (p2 + p3);
                else         lsum1 += (p0 + p1) + (p2 + p3);
                ushort4 pw;
                pw.x = f2bf_fast(p0);
                pw.y = f2bf_fast(p1);
                pw.z = f2bf_fast(p2);
                pw.w = f2bf_fast(p3);
                // data chunk c = 2*nt + (quad>>1) (kv = c*8 + (quad&1)*4 + r)
                const int pos = (2 * nt + (quad >> 1) + (prow >> 1)) & 3;
                *(ushort4*)&ps[prow * 32 + pos * 8 + (quad & 1) * 4] = pw;
            }
        }

        // ---- PV: ctx^T += MFMA(V^T, P); one 32-kv k-step; vf reused ------
        short8 pf0 = ldP(ps, prow0,      quad);
        short8 pf1 = ldP(ps, prow0 + 16, quad);
#pragma unroll
        for (int dt = 0; dt < 4; ++dt) {
            short8 vf = ldK(vsm[vcur], dt * 16 + lnid, half * 4 + quad);
            ctx[0][dt] = MFMA16(vf, pf0, ctx[0][dt]);
            ctx[1][dt] = MFMA16(vf, pf1, ctx[1][dt]);
        }
    }

    // ---- row sums (reduce over quads: 2 shuffles), packed ushort4 stores --
#pragma unroll
    for (int rg = 0; rg < 2; ++rg) {
        float s = (rg == 0) ? lsum0 : lsum1;
        s += __shfl_xor(s, 16, 64);
        s += __shfl_xor(s, 32, 64);
        const float inv = 1.0f / s;
        const int srow = b * SEQ + q0 + prow0 + rg * 16;
#pragma unroll
        for (int dt = 0; dt < 4; ++dt) {
            ushort4 pk;
            pk.x = f2bf(ctx[rg][dt][0] * inv);
            pk.y = f2bf(ctx[rg][dt][1] * inv);
            pk.z = f2bf(ctx[rg][dt][2] * inv);
            pk.w = f2bf(ctx[rg][dt][3] * inv);
            *(ushort4*)&ctb[(size_t)srow * DM + h * DHD + dt * 16 + quad * 4] = pk;
        }
    }
}

// ---------------------------------------------------------------------------
// Kernel 3: output projection. Tile 128x64, BK=64, single-buffered,
// transposed orientation -> float4 stores. Grid (64, 12) = 768 blocks.
// UNCHANGED from R6.
// ---------------------------------------------------------------------------
__global__ __launch_bounds__(256, 3) void out_mfma_k(
    const unsigned short* __restrict__ ctb, const unsigned short* __restrict__ wot,
    const float* __restrict__ bo, float* __restrict__ out) {
    __shared__ unsigned short Ah[128 * 64], Bh[64 * 64];   // 16 KB + 8 KB

    const int tid = threadIdx.x;
    const int wv = tid >> 6, ln = tid & 63, quad = ln >> 4, lnid = ln & 15;
    const int wvm = wv >> 1, wvn = wv & 1;
    const int row0 = blockIdx.x * 128, col0 = blockIdx.y * 64;

    f32x4 acc[2][4];   // [jt][it]: D rows = outcol, cols = srow
#pragma unroll
    for (int j = 0; j < 2; ++j)
#pragma unroll
        for (int i = 0; i < 4; ++i) acc[j][i] = (f32x4){0.f, 0.f, 0.f, 0.f};

    const unsigned short* Ahg = ctb + (size_t)row0 * DM;
    const unsigned short* Bhg = wot + (size_t)col0 * DM;

    constexpr int NIT = DM / 64;  // 12
    for (int it = 0; it < NIT; ++it) {
        const int kc = it * 64;
        __syncthreads();
#pragma unroll
        for (int c = 0; c < 4; ++c) stageK(Ah, Ahg + kc, wv * 4 + c, ln, DM);
#pragma unroll
        for (int c = 0; c < 2; ++c) stageK(Bh, Bhg + kc, wv * 2 + c, ln, DM);
        __syncthreads();
#pragma unroll
        for (int ks = 0; ks < 2; ++ks) {
            short8 a[4], b[2];
#pragma unroll
            for (int i = 0; i < 4; ++i)
                a[i] = ldK(Ah, wvm * 64 + i * 16 + lnid, ks * 4 + quad);
#pragma unroll
            for (int j = 0; j < 2; ++j)
                b[j] = ldK(Bh, wvn * 32 + j * 16 + lnid, ks * 4 + quad);
#pragma unroll
            for (int j = 0; j < 2; ++j)
#pragma unroll
                for (int i = 0; i < 4; ++i)
                    acc[j][i] = MFMA16(b[j], a[i], acc[j][i]);
        }
    }

#pragma unroll
    for (int jt = 0; jt < 2; ++jt) {
        const int colb = col0 + wvn * 32 + jt * 16 + quad * 4;
        float4 bs = *(const float4*)&bo[colb];
#pragma unroll
        for (int it = 0; it < 4; ++it) {
            const int srow = row0 + wvm * 64 + it * 16 + lnid;
            float4 o;
            o.x = acc[jt][it][0] + bs.x;
            o.y = acc[jt][it][1] + bs.y;
            o.z = acc[jt][it][2] + bs.z;
            o.w = acc[jt][it][3] + bs.w;
            *(float4*)&out[(size_t)srow * DM + colb] = o;
        }
    }
}

// ---------------------------------------------------------------------------
extern "C" void kernel_launch(void* const* d_in, const int* in_sizes, int n_in,
                              void* d_out, int out_size, void* d_ws, size_t ws_size,
                              hipStream_t stream) {
    const float* x  = (const float*)d_in[0];
    const float* Wq = (const float*)d_in[1];
    const float* Wk = (const float*)d_in[2];
    const float* Wv = (const float*)d_in[3];
    const float* bq = (const float*)d_in[4];
    const float* bk = (const float*)d_in[5];
    const float* bv = (const float*)d_in[6];
    const float* Wo = (const float*)d_in[7];
    const float* bo = (const float*)d_in[8];
    float* out = (float*)d_out;

    // workspace: xb | wt | wot | qb | kb | vT. ctb aliases xb (disjoint lifetime).
    char* w = (char*)d_ws;
    const size_t elsX = (size_t)MROWS * DM;          // 6,291,456
    const size_t elsQ = (size_t)NB * NH * SEQ * DHD; // 6,291,456
    unsigned short* xb  = (unsigned short*)w;
    unsigned short* ctb = xb;  // alias, disjoint lifetime
    size_t off = elsX * 2;
    unsigned short* wt  = (unsigned short*)(w + off); off += (size_t)NQKV * DM * 2;
    unsigned short* wot = (unsigned short*)(w + off); off += (size_t)DM * DM * 2;
    unsigned short* qbp = (unsigned short*)(w + off); off += elsQ * 2;
    unsigned short* kbp = (unsigned short*)(w + off); off += elsQ * 2;
    unsigned short* vTp = (unsigned short*)(w + off); off += elsQ * 2;

    prep_k<<<dim3(6144 + 576), 256, 0, stream>>>(x, Wq, Wk, Wv, Wo, xb, wt, wot);
    qkv_mfma_k<<<dim3(MROWS / 128, NQKV / 128), 256, 0, stream>>>(
        xb, wt, bq, bk, bv, qbp, kbp, vTp);
    attn_mfma_k<<<dim3(768), 256, 0, stream>>>(qbp, kbp, vTp, ctb);
    out_mfma_k<<<dim3(MROWS / 128, DM / 64), 256, 0, stream>>>(ctb, wot, bo, out);
}

// Round 10
// 190.133 us; speedup vs baseline: 1.5123x; 1.0373x over previous
//
#include <hip/hip_runtime.h>
#include <math.h>

// ---------------------------------------------------------------------------
// MultiHeadAttention: B=8, S=1024, H=12, D=768, DH=64. fp32 in/out.
// R17: attn closed out — six structures bracketed, R7 (8wx16q KVBLK=64 dbuf)
// = 43.0 us is the family floor (KVBLK=32 halved MFMA-per-barrier: 54.6).
// attn/qkv reverted to their best measured kernels. Experiment: out
// projection widened 128x64 -> 128x128 tile (exact qkv sel<2 loop, fp32
// float4 epilogue): doubles MFMA per staged byte, grid (64,6)=384 blocks
// all co-resident. Delta-total isolates delta-out. prep unchanged.
// ---------------------------------------------------------------------------

constexpr int NB  = 8;
constexpr int SEQ = 1024;
constexpr int NH  = 12;
constexpr int DM  = 768;
constexpr int DHD = 64;
constexpr int MROWS = NB * SEQ;      // 8192
constexpr int NQKV  = 3 * NH * DHD;  // 2304

typedef __attribute__((ext_vector_type(8))) short short8;
typedef __attribute__((ext_vector_type(4))) float f32x4;

#define MFMA16(a,b,c) __builtin_amdgcn_mfma_f32_16x16x32_bf16((a),(b),(c),0,0,0)

#if __has_builtin(__builtin_amdgcn_exp2f)
#define EXP2(x) __builtin_amdgcn_exp2f(x)
#else
#define EXP2(x) exp2f(x)
#endif

// RNE float->bf16
__device__ __forceinline__ unsigned short f2bf(float f) {
    unsigned u = __float_as_uint(f);
    return (unsigned short)((u + 0x7fffu + ((u >> 16) & 1u)) >> 16);
}
// round-half-up float->bf16 (2 VALU) — P in the attention hot loop
__device__ __forceinline__ unsigned short f2bf_fast(float f) {
    return (unsigned short)((__float_as_uint(f) + 0x8000u) >> 16);
}

// async 16B/lane global->LDS (LDS dest wave-uniform base + lane*16)
__device__ __forceinline__ void gl_lds16(const unsigned short* g, unsigned short* l) {
    __builtin_amdgcn_global_load_lds(
        (const __attribute__((address_space(1))) void*)g,
        (__attribute__((address_space(3))) void*)l, 16, 0, 0);
}

// 128B-row tiles ([rows][64] bf16), swizzle: chunk at pos (c+r)&7.
// One call stages rows [i*8, i*8+8) (1 KB).
__device__ __forceinline__ void stageK(unsigned short* lds, const unsigned short* gbase,
                                       int i, int ln, int ldg) {
    int r    = i * 8 + (ln >> 3);
    int cpos = ln & 7;
    int cdat = (cpos - r) & 7;
    gl_lds16(gbase + (size_t)r * ldg + cdat * 8, lds + i * 512);
}
__device__ __forceinline__ short8 ldK(const unsigned short* buf, int row, int chunk) {
    int c = (chunk + row) & 7;
    return *(const short8*)&buf[row * 64 + c * 8];
}

// ---------------------------------------------------------------------------
// Fused prep: blocks [0,6144) convert x fp32->bf16; blocks [6144,6720)
// transpose+convert Wq/Wk/Wv (per-head [768][64] -> [64][768]) and Wo.
// ---------------------------------------------------------------------------
__global__ __launch_bounds__(256) void prep_k(
    const float* __restrict__ x,
    const float* __restrict__ Wq, const float* __restrict__ Wk,
    const float* __restrict__ Wv, const float* __restrict__ Wo,
    unsigned short* __restrict__ xb, unsigned short* __restrict__ wt,
    unsigned short* __restrict__ wot) {
    __shared__ float tb[64][65];
    const int blk = blockIdx.x, tid = threadIdx.x;
    if (blk < 6144) {  // x conversion: 6144*256 float4 = elsX
        const int i = blk * 256 + tid;
        float4 v = ((const float4*)x)[i];
        ushort4 o;
        o.x = f2bf(v.x); o.y = f2bf(v.y); o.z = f2bf(v.z); o.w = f2bf(v.w);
        ((ushort4*)xb)[i] = o;
        return;
    }
    const int t = blk - 6144;       // 0..575
    const int job = t / 144, lb = t % 144;
    const float* W;
    unsigned short* dst;
    int C, r0, c0;
    if (job < 3) {
        const float* Ws = (job == 0) ? Wq : (job == 1 ? Wk : Wv);
        const int h = lb / 12, rb = lb % 12;
        W = Ws + (size_t)h * (DM * DHD);                // [768][64]
        dst = wt + (size_t)(job * 12 + h) * (DM * DHD); // rows = e, cols = d
        C = DHD; r0 = rb * 64; c0 = 0;
    } else {
        W = Wo; dst = wot; C = DM;
        r0 = (lb / 12) * 64; c0 = (lb % 12) * 64;
    }
    const int rr = tid >> 2, cc = (tid & 3) * 16;
#pragma unroll
    for (int j = 0; j < 16; j += 4) {
        float4 v = *(const float4*)&W[(size_t)(r0 + rr) * C + c0 + cc + j];
        tb[rr][cc + j + 0] = v.x;
        tb[rr][cc + j + 1] = v.y;
        tb[rr][cc + j + 2] = v.z;
        tb[rr][cc + j + 3] = v.w;
    }
    __syncthreads();
#pragma unroll
    for (int j = 0; j < 16; ++j)
        dst[(size_t)(c0 + rr) * DM + r0 + cc + j] = f2bf(tb[cc + j][rr]);
}

// ---------------------------------------------------------------------------
// Kernel 1: QKV projection. Tile 128x128, BK=64, single-buffered, 2x2 waves.
// q/k blocks transposed orientation (packed ushort4 epilogue); v normal
// (packed along seq into vT). Grid (64, 18). EXACT R0 kernel (43.0 us).
// ---------------------------------------------------------------------------
__global__ __launch_bounds__(256, 3) void qkv_mfma_k(
    const unsigned short* __restrict__ xb, const unsigned short* __restrict__ wt,
    const float* __restrict__ bq, const float* __restrict__ bk, const float* __restrict__ bv,
    unsigned short* __restrict__ qb, unsigned short* __restrict__ kb,
    unsigned short* __restrict__ vT) {
    __shared__ unsigned short Ah[128 * 64], Bh[128 * 64];   // 16 KB + 16 KB

    const int tid = threadIdx.x;
    const int wv = tid >> 6, ln = tid & 63, quad = ln >> 4, lnid = ln & 15;
    const int wvm = wv >> 1, wvn = wv & 1;
    const int row0 = blockIdx.x * 128, col0 = blockIdx.y * 128;
    const int sel = (col0 >= 2 * DM) ? 2 : (col0 >= DM ? 1 : 0);

    f32x4 acc[4][4];
#pragma unroll
    for (int i = 0; i < 4; ++i)
#pragma unroll
        for (int j = 0; j < 4; ++j) acc[i][j] = (f32x4){0.f, 0.f, 0.f, 0.f};

    const unsigned short* Ahg = xb + (size_t)row0 * DM;
    const unsigned short* Bhg = wt + (size_t)col0 * DM;
    constexpr int NIT = DM / 64;  // 12

    if (sel < 2) {
        // ---- transposed: acc[et][st], D rows = e, cols = srow ----
        for (int it = 0; it < NIT; ++it) {
            const int kc = it * 64;
            __syncthreads();
#pragma unroll
            for (int c = 0; c < 4; ++c) {
                stageK(Ah, Ahg + kc, wv * 4 + c, ln, DM);
                stageK(Bh, Bhg + kc, wv * 4 + c, ln, DM);
            }
            __syncthreads();
#pragma unroll
            for (int ks = 0; ks < 2; ++ks) {
                short8 a[4], b[4];
#pragma unroll
                for (int i = 0; i < 4; ++i)
                    a[i] = ldK(Ah, wvm * 64 + i * 16 + lnid, ks * 4 + quad);
#pragma unroll
                for (int j = 0; j < 4; ++j)
                    b[j] = ldK(Bh, wvn * 64 + j * 16 + lnid, ks * 4 + quad);
#pragma unroll
                for (int j = 0; j < 4; ++j)
#pragma unroll
                    for (int i = 0; i < 4; ++i)
                        acc[j][i] = MFMA16(b[j], a[i], acc[j][i]);
            }
        }
        // q prescale folds 1/sqrt(64) and log2(e) so softmax is bare exp2
        const float scale = (sel == 0) ? 0.18033688011112042f : 1.0f;
        const float* bias = (sel == 0) ? bq : bk;
        unsigned short* oh = (sel == 0) ? qb : kb;
#pragma unroll
        for (int et = 0; et < 4; ++et) {
            const int e = col0 + wvn * 64 + et * 16 + quad * 4;
            const int he = e - sel * DM;
            const int hh2 = he >> 6, ee = he & 63;
            float4 bs = *(const float4*)&bias[he];
#pragma unroll
            for (int st = 0; st < 4; ++st) {
                const int srow = row0 + wvm * 64 + st * 16 + lnid;
                const int bb = srow >> 10, ss = srow & (SEQ - 1);
                ushort4 pk;
                pk.x = f2bf((acc[et][st][0] + bs.x) * scale);
                pk.y = f2bf((acc[et][st][1] + bs.y) * scale);
                pk.z = f2bf((acc[et][st][2] + bs.z) * scale);
                pk.w = f2bf((acc[et][st][3] + bs.w) * scale);
                *(ushort4*)&oh[((size_t)(bb * NH + hh2) * SEQ + ss) * DHD + ee] = pk;
            }
        }
    } else {
        // ---- normal: acc[st][et], D rows = srow, cols = e; packed along s ----
        for (int it = 0; it < NIT; ++it) {
            const int kc = it * 64;
            __syncthreads();
#pragma unroll
            for (int c = 0; c < 4; ++c) {
                stageK(Ah, Ahg + kc, wv * 4 + c, ln, DM);
                stageK(Bh, Bhg + kc, wv * 4 + c, ln, DM);
            }
            __syncthreads();
#pragma unroll
            for (int ks = 0; ks < 2; ++ks) {
                short8 a[4], b[4];
#pragma unroll
                for (int i = 0; i < 4; ++i)
                    a[i] = ldK(Ah, wvm * 64 + i * 16 + lnid, ks * 4 + quad);
#pragma unroll
                for (int j = 0; j < 4; ++j)
                    b[j] = ldK(Bh, wvn * 64 + j * 16 + lnid, ks * 4 + quad);
#pragma unroll
                for (int i = 0; i < 4; ++i)
#pragma unroll
                    for (int j = 0; j < 4; ++j)
                        acc[i][j] = MFMA16(a[i], b[j], acc[i][j]);
            }
        }
#pragma unroll
        for (int i = 0; i < 4; ++i) {
#pragma unroll
            for (int j = 0; j < 4; ++j) {
                const int col = col0 + wvn * 64 + j * 16 + lnid;
                const int he = col - 2 * DM;
                const int hh2 = he >> 6, ee = he & 63;
                const float bs = bv[he];
                const int srow = row0 + wvm * 64 + i * 16 + quad * 4;
                const int bb = srow >> 10, ss = srow & (SEQ - 1);
                ushort4 pk;
                pk.x = f2bf(acc[i][j][0] + bs);
                pk.y = f2bf(acc[i][j][1] + bs);
                pk.z = f2bf(acc[i][j][2] + bs);
                pk.w = f2bf(acc[i][j][3] + bs);
                *(ushort4*)&vT[((size_t)(bb * NH + hh2) * DHD + ee) * SEQ + ss] = pk;
            }
        }
    }
}

// ---------------------------------------------------------------------------
// Kernel 2: flash attention. 512 threads = 8 waves, each wave 16 q-rows.
// Q-tile 128, KV-step 64, K/V double-buffered; 2 stageK calls/wave/iter.
// S^T = MFMA(K,Q); ps XOR-8 swizzled [128][64] (wave-private rows, no extra
// barrier); PV: ctx^T = MFMA(V^T, P). Grid 768 1-D, bh = blk % 96 fastest
// (XCD-local KV). LDS: 16 + 16 + 16 = 48 KB -> 3 blocks/CU = 24 waves/CU.
// EXACT R7 kernel (measured 43.0 us; family floor after 6-structure sweep).
// ---------------------------------------------------------------------------
__global__ __launch_bounds__(512, 6) void attn_mfma_k(
    const unsigned short* __restrict__ qb, const unsigned short* __restrict__ kb,
    const unsigned short* __restrict__ vT, unsigned short* __restrict__ ctb) {
    __shared__ unsigned short ksh[2][64 * 64], vsm[2][64 * 64];
    __shared__ unsigned short ps[128 * 64];   // XOR-8 swizzled

    const int tid = threadIdx.x;
    const int wv = tid >> 6, ln = tid & 63, quad = ln >> 4, lnid = ln & 15;
    const int bhid = blockIdx.x % 96, qt = blockIdx.x / 96;
    const int b = bhid / NH, h = bhid % NH;
    const int q0 = qt * 128;
    const unsigned short* qhb = qb + (size_t)bhid * (SEQ * DHD);
    const unsigned short* khb = kb + (size_t)bhid * (SEQ * DHD);
    const unsigned short* vTb = vT + (size_t)bhid * (DHD * SEQ);

    const int prow = wv * 16 + lnid;   // this lane's block-local q-row

    // persistent q fragment (B-operand: lane&15 = qrow) [kstep]
    short8 qf[2];
#pragma unroll
    for (int ks_ = 0; ks_ < 2; ++ks_)
        qf[ks_] = *(const short8*)(qhb + (size_t)(q0 + prow) * DHD + ks_ * 32 + quad * 8);

    f32x4 ctx[4];   // [dt]: D rows = d, cols = qrow
#pragma unroll
    for (int j = 0; j < 4; ++j) ctx[j] = (f32x4){0.f, 0.f, 0.f, 0.f};
    float lsum = 0.f;

    // prefetch tile 0 into buffer 0 (wave wv stages rows [wv*8, wv*8+8))
    stageK(ksh[0], khb, wv, ln, DHD);
    stageK(vsm[0], vTb, wv, ln, SEQ);

    for (int kt = 0; kt < SEQ / 64; ++kt) {
        const int cur = kt & 1;
        __syncthreads();   // buf[cur] ready; prev readers of buf[cur^1] done
        if (kt + 1 < SEQ / 64) {
            stageK(ksh[cur ^ 1], khb + (kt + 1) * 64 * DHD, wv, ln, DHD);
            stageK(vsm[cur ^ 1], vTb + (kt + 1) * 64, wv, ln, SEQ);
        }

        // ---- scores S^T: sc[nt] rows = j (nt*16+quad*4+r), cols = qrow ----
        f32x4 sc[4];
#pragma unroll
        for (int j = 0; j < 4; ++j) sc[j] = (f32x4){0.f, 0.f, 0.f, 0.f};
#pragma unroll
        for (int ks_ = 0; ks_ < 2; ++ks_) {
#pragma unroll
            for (int nt = 0; nt < 4; ++nt) {
                short8 kf = ldK(ksh[cur], nt * 16 + lnid, ks_ * 4 + quad);
                sc[nt] = MFMA16(kf, qf[ks_], sc[nt]);
            }
        }

        // ---- p = 2^s; per-lane sums; swizzled b64 P-writes (wave-private) ----
#pragma unroll
        for (int nt = 0; nt < 4; ++nt) {
            float p0 = EXP2(sc[nt][0]);
            float p1 = EXP2(sc[nt][1]);
            float p2 = EXP2(sc[nt][2]);
            float p3 = EXP2(sc[nt][3]);
            lsum += (p0 + p1) + (p2 + p3);
            ushort4 pw;
            pw.x = f2bf_fast(p0);
            pw.y = f2bf_fast(p1);
            pw.z = f2bf_fast(p2);
            pw.w = f2bf_fast(p3);
            // chunk cdat = 2*nt + (quad>>1), swizzled pos (cdat + prow) & 7
            const int cpos = (2 * nt + (quad >> 1) + prow) & 7;
            *(ushort4*)&ps[prow * 64 + cpos * 8 + (quad & 1) * 4] = pw;
        }

        // ---- PV: ctx^T += MFMA(V^T, P) ----
#pragma unroll
        for (int kvs = 0; kvs < 2; ++kvs) {
            short8 pf = ldK(ps, prow, kvs * 4 + quad);
#pragma unroll
            for (int dt = 0; dt < 4; ++dt) {
                short8 vf = ldK(vsm[cur], dt * 16 + lnid, kvs * 4 + quad);
                ctx[dt] = MFMA16(vf, pf, ctx[dt]);
            }
        }
    }

    // ---- row sum (reduce over quads: 2 shuffles), packed ushort4 stores ----
    float s = lsum;
    s += __shfl_xor(s, 16, 64);
    s += __shfl_xor(s, 32, 64);
    const float inv = 1.0f / s;
    const int srow = b * SEQ + q0 + prow;
#pragma unroll
    for (int dt = 0; dt < 4; ++dt) {
        ushort4 pk;
        pk.x = f2bf(ctx[dt][0] * inv);
        pk.y = f2bf(ctx[dt][1] * inv);
        pk.z = f2bf(ctx[dt][2] * inv);
        pk.w = f2bf(ctx[dt][3] * inv);
        *(ushort4*)&ctb[(size_t)srow * DM + h * DHD + dt * 16 + quad * 4] = pk;
    }
}

// ---------------------------------------------------------------------------
// Kernel 3: output projection, tile 128x128 (was 128x64): exact qkv sel<2
// loop (32 MFMA/wave/iter vs 16 — double MFMA per staged byte), fp32 float4
// epilogue. Grid (64, 6) = 384 blocks, all co-resident at 3 blocks/CU.
// ---------------------------------------------------------------------------
__global__ __launch_bounds__(256, 3) void out_mfma_k(
    const unsigned short* __restrict__ ctb, const unsigned short* __restrict__ wot,
    const float* __restrict__ bo, float* __restrict__ out) {
    __shared__ unsigned short Ah[128 * 64], Bh[128 * 64];   // 16 KB + 16 KB

    const int tid = threadIdx.x;
    const int wv = tid >> 6, ln = tid & 63, quad = ln >> 4, lnid = ln & 15;
    const int wvm = wv >> 1, wvn = wv & 1;
    const int row0 = blockIdx.x * 128, col0 = blockIdx.y * 128;

    f32x4 acc[4][4];   // [et][st]: D rows = outcol, cols = srow (transposed)
#pragma unroll
    for (int i = 0; i < 4; ++i)
#pragma unroll
        for (int j = 0; j < 4; ++j) acc[i][j] = (f32x4){0.f, 0.f, 0.f, 0.f};

    const unsigned short* Ahg = ctb + (size_t)row0 * DM;
    const unsigned short* Bhg = wot + (size_t)col0 * DM;

    constexpr int NIT = DM / 64;  // 12
    for (int it = 0; it < NIT; ++it) {
        const int kc = it * 64;
        __syncthreads();
#pragma unroll
        for (int c = 0; c < 4; ++c) {
            stageK(Ah, Ahg + kc, wv * 4 + c, ln, DM);
            stageK(Bh, Bhg + kc, wv * 4 + c, ln, DM);
        }
        __syncthreads();
#pragma unroll
        for (int ks = 0; ks < 2; ++ks) {
            short8 a[4], b[4];
#pragma unroll
            for (int i = 0; i < 4; ++i)
                a[i] = ldK(Ah, wvm * 64 + i * 16 + lnid, ks * 4 + quad);
#pragma unroll
            for (int j = 0; j < 4; ++j)
                b[j] = ldK(Bh, wvn * 64 + j * 16 + lnid, ks * 4 + quad);
#pragma unroll
            for (int j = 0; j < 4; ++j)
#pragma unroll
                for (int i = 0; i < 4; ++i)
                    acc[j][i] = MFMA16(b[j], a[i], acc[j][i]);
        }
    }

#pragma unroll
    for (int et = 0; et < 4; ++et) {
        const int colb = col0 + wvn * 64 + et * 16 + quad * 4;
        float4 bs = *(const float4*)&bo[colb];
#pragma unroll
        for (int st = 0; st < 4; ++st) {
            const int srow = row0 + wvm * 64 + st * 16 + lnid;
            float4 o;
            o.x = acc[et][st][0] + bs.x;
            o.y = acc[et][st][1] + bs.y;
            o.z = acc[et][st][2] + bs.z;
            o.w = acc[et][st][3] + bs.w;
            *(float4*)&out[(size_t)srow * DM + colb] = o;
        }
    }
}

// ---------------------------------------------------------------------------
extern "C" void kernel_launch(void* const* d_in, const int* in_sizes, int n_in,
                              void* d_out, int out_size, void* d_ws, size_t ws_size,
                              hipStream_t stream) {
    const float* x  = (const float*)d_in[0];
    const float* Wq = (const float*)d_in[1];
    const float* Wk = (const float*)d_in[2];
    const float* Wv = (const float*)d_in[3];
    const float* bq = (const float*)d_in[4];
    const float* bk = (const float*)d_in[5];
    const float* bv = (const float*)d_in[6];
    const float* Wo = (const float*)d_in[7];
    const float* bo = (const float*)d_in[8];
    float* out = (float*)d_out;

    // workspace: xb | wt | wot | qb | kb | vT. ctb aliases xb (disjoint lifetime).
    char* w = (char*)d_ws;
    const size_t elsX = (size_t)MROWS * DM;          // 6,291,456
    const size_t elsQ = (size_t)NB * NH * SEQ * DHD; // 6,291,456
    unsigned short* xb  = (unsigned short*)w;
    unsigned short* ctb = xb;  // alias, disjoint lifetime
    size_t off = elsX * 2;
    unsigned short* wt  = (unsigned short*)(w + off); off += (size_t)NQKV * DM * 2;
    unsigned short* wot = (unsigned short*)(w + off); off += (size_t)DM * DM * 2;
    unsigned short* qbp = (unsigned short*)(w + off); off += elsQ * 2;
    unsigned short* kbp = (unsigned short*)(w + off); off += elsQ * 2;
    unsigned short* vTp = (unsigned short*)(w + off); off += elsQ * 2;

    prep_k<<<dim3(6144 + 576), 256, 0, stream>>>(x, Wq, Wk, Wv, Wo, xb, wt, wot);
    qkv_mfma_k<<<dim3(MROWS / 128, NQKV / 128), 256, 0, stream>>>(
        xb, wt, bq, bk, bv, qbp, kbp, vTp);
    attn_mfma_k<<<dim3(768), 512, 0, stream>>>(qbp, kbp, vTp, ctb);
    out_mfma_k<<<dim3(MROWS / 128, DM / 128), 256, 0, stream>>>(ctb, wot, bo, out);
}